// Round 1
// baseline (176.521 us; speedup 1.0000x reference)
//
#include <hip/hip_runtime.h>
#include <stdint.h>

#define NB_LAYERS 4
#define KSIZE 5
#define BSZ 8
#define LIN 2048
#define LSEQ 2049
#define CCH 32
#define HCH 16
#define MROWS (BSZ*LSEQ)          // 16392
#define NTILES ((MROWS+15)/16)    // 1025
#define KDIM 576                  // 512 (h*c) + 32 (k3b block) + 32 (skip block)
#define NEG 0.1f
#define BNEPS 1e-5f

typedef _Float16 h2v __attribute__((ext_vector_type(2)));
typedef _Float16 h8v __attribute__((ext_vector_type(8)));
typedef float    f4v __attribute__((ext_vector_type(4)));

union H8 { h8v v; h2v h[4]; };

static __device__ __forceinline__ h2v mkh2(float a, float b) {
  h2v r; r[0] = (_Float16)a; r[1] = (_Float16)b; return r;
}

// ---------------- init: zero BN stats + max-type ----------------
__global__ void init_kernel(float* stats, int* maxp) {
  int i = blockIdx.x * blockDim.x + threadIdx.x;
  if (i < NB_LAYERS * 64) stats[i] = 0.f;
  if (i == 0) *maxp = 0;
}

// ---------------- max over event_types ----------------
__global__ void max_kernel(const int* __restrict__ types, int* maxp) {
  int i = blockIdx.x * blockDim.x + threadIdx.x;
  int v = 0;
  if (i < BSZ * LIN) v = types[i];
#pragma unroll
  for (int off = 32; off; off >>= 1) v = max(v, __shfl_xor(v, off, 64));
  if ((threadIdx.x & 63) == 0) atomicMax(maxp, v);
}

// ---------------- build transposed fp16 weight table Wt[layer][n=32][k=576] ----------------
// k<512: q=h*32+c -> k3W[h, c*32+n]; 512..543: k3b[c*32+n]; 544..575: skipW[c, n]
__global__ void prep_kernel(const float* __restrict__ k3W, const float* __restrict__ k3b,
                            const float* __restrict__ skipW, _Float16* __restrict__ Wt) {
  int id = blockIdx.x * blockDim.x + threadIdx.x;
  if (id >= NB_LAYERS * CCH * KDIM) return;
  int layer = id / (CCH * KDIM);
  int rem = id % (CCH * KDIM);
  int n = rem / KDIM;
  int k = rem % KDIM;
  float val;
  if (k < 512)      { int h = k >> 5, c = k & 31; val = k3W[layer*16384 + h*1024 + c*32 + n]; }
  else if (k < 544) { int c = k - 512;            val = k3b[layer*1024 + c*32 + n]; }
  else              { int c = k - 544;            val = skipW[layer*1024 + c*32 + n]; }
  Wt[id] = (_Float16)val;
}

// ---------------- embedding lookup ----------------
__global__ void embed_kernel(const int* __restrict__ types, const float* __restrict__ emb,
                             const int* __restrict__ maxp, float* __restrict__ enc) {
  int id = blockIdx.x * blockDim.x + threadIdx.x;
  if (id >= MROWS * CCH) return;
  int row = id >> 5, c = id & 31;
  int b = row / LSEQ, pos = row % LSEQ;
  int t = (pos == 0) ? (*maxp + 1) : types[b * LIN + pos - 1];
  enc[id] = (t == 0) ? 0.f : emb[t * CCH + c];
}

// ---------------- fused cont-conv layer: taps + MLP + MFMA GEMM + BN-stats ----------------
__global__ __launch_bounds__(256) void conv_kernel(
    const float* __restrict__ enc_in, float* __restrict__ enc_out,
    const float* __restrict__ etimes,
    const float* __restrict__ k1Wp, const float* __restrict__ k1bp,
    const float* __restrict__ k2Wp, const float* __restrict__ k2bp,
    const _Float16* __restrict__ Wt,      // this layer's 32x576 fp16 table
    float* __restrict__ stats, int dil)
{
  __shared__ float sst[64];
  if (threadIdx.x < 64) sst[threadIdx.x] = 0.f;
  __syncthreads();

  const int lane = threadIdx.x & 63;
  const int wv   = threadIdx.x >> 6;
  const int m    = lane & 15;     // A-frag row within tile / B-frag col n
  const int q    = lane >> 4;     // quad: k-subchunk + feat channels q*8..q*8+7

  // MLP params (uniform -> scalar regs)
  float k1w[HCH], k1b[HCH], k2b[HCH];
#pragma unroll
  for (int h = 0; h < HCH; h++) { k1w[h] = k1Wp[h]; k1b[h] = k1bp[h]; k2b[h] = k2bp[h]; }

  const _Float16* wb0 = Wt + m * KDIM + q * 8;
  const _Float16* wb1 = Wt + (m + 16) * KDIM + q * 8;

  for (int tile = blockIdx.x * 4 + wv; tile < NTILES; tile += gridDim.x * 4) {
    int row = tile * 16 + m;
    bool rvalid = row < MROWS;
    int rowc = min(row, MROWS - 1);
    int b = rowc / LSEQ, pos = rowc % LSEQ;
    float t_l = (pos == 0) ? 0.f : etimes[b * LIN + pos - 1];
    bool mask_l = rvalid && (t_l != 0.f);

    h2v wh[KSIZE][8];     // gm * h2  (fp16 pairs)
    h2v fh[KSIZE][4];     // gathered feats (fp16 pairs)
    h2v fself[4];
    float Fb[8];
#pragma unroll
    for (int jj = 0; jj < 8; jj++) Fb[jj] = 0.f;

#pragma unroll
    for (int tap = 0; tap < KSIZE; tap++) {
      int j = pos - tap * dil;
      int jc = max(j, 0);
      float t_j = (jc == 0) ? 0.f : etimes[b * LIN + jc - 1];
      bool gm = mask_l && (j >= 0) && (t_j != 0.f);
      float dt = gm ? (t_l - t_j) : 0.f;

      const float* fp = enc_in + (b * LSEQ + jc) * CCH + q * 8;
      float4 fA = *(const float4*)(fp);
      float4 fB = *(const float4*)(fp + 4);
      float fv[8] = {fA.x, fA.y, fA.z, fA.w, fB.x, fB.y, fB.z, fB.w};

      if (tap == 0) {
        float rv = rvalid ? 1.f : 0.f;
#pragma unroll
        for (int p = 0; p < 4; p++) fself[p] = mkh2(fv[2*p] * rv, fv[2*p+1] * rv);
      }
      float g = gm ? 1.f : 0.f;
#pragma unroll
      for (int jj = 0; jj < 8; jj++) Fb[jj] += g * fv[jj];
#pragma unroll
      for (int p = 0; p < 4; p++) fh[tap][p] = mkh2(fv[2*p], fv[2*p+1]);

      if (__ballot(gm)) {
        float h1[HCH];
#pragma unroll
        for (int h = 0; h < HCH; h++) { float x = fmaf(dt, k1w[h], k1b[h]); h1[h] = fmaxf(x, NEG * x); }
        float h2[HCH];
#pragma unroll
        for (int h = 0; h < HCH; h++) h2[h] = k2b[h];
#pragma unroll
        for (int hp = 0; hp < HCH; hp++) {
          float hv = h1[hp];
#pragma unroll
          for (int h = 0; h < HCH; h++) h2[h] = fmaf(hv, k2Wp[hp * HCH + h], h2[h]);
        }
#pragma unroll
        for (int hh = 0; hh < 8; hh++) {
          float a = h2[2*hh];     a = fmaxf(a, NEG * a) * g;
          float c2 = h2[2*hh+1];  c2 = fmaxf(c2, NEG * c2) * g;
          wh[tap][hh] = mkh2(a, c2);
        }
      } else {
#pragma unroll
        for (int hh = 0; hh < 8; hh++) wh[tap][hh] = mkh2(0.f, 0.f);
      }
    }

    f4v acc0 = {0.f, 0.f, 0.f, 0.f};
    f4v acc1 = {0.f, 0.f, 0.f, 0.f};

#pragma unroll
    for (int ks = 0; ks < 16; ks++) {
      H8 bf0, bf1, af;
      bf0.v = *(const h8v*)(wb0 + ks * 32);
      bf1.v = *(const h8v*)(wb1 + ks * 32);
      h2v u0 = mkh2(0.f,0.f), u1 = mkh2(0.f,0.f), u2 = mkh2(0.f,0.f), u3 = mkh2(0.f,0.f);
#pragma unroll
      for (int tap = 0; tap < KSIZE; tap++) {
        _Float16 w = wh[tap][ks >> 1][ks & 1];
        h2v wd; wd[0] = w; wd[1] = w;
        u0 += wd * fh[tap][0];
        u1 += wd * fh[tap][1];
        u2 += wd * fh[tap][2];
        u3 += wd * fh[tap][3];
      }
      af.h[0] = u0; af.h[1] = u1; af.h[2] = u2; af.h[3] = u3;
      acc0 = __builtin_amdgcn_mfma_f32_16x16x32_f16(af.v, bf0.v, acc0, 0, 0, 0);
      acc1 = __builtin_amdgcn_mfma_f32_16x16x32_f16(af.v, bf1.v, acc1, 0, 0, 0);
    }
    { // k3b block (k = 512..543)
      H8 bf0, bf1, af;
      bf0.v = *(const h8v*)(wb0 + 512);
      bf1.v = *(const h8v*)(wb1 + 512);
#pragma unroll
      for (int p = 0; p < 4; p++) af.h[p] = mkh2(Fb[2*p], Fb[2*p+1]);
      acc0 = __builtin_amdgcn_mfma_f32_16x16x32_f16(af.v, bf0.v, acc0, 0, 0, 0);
      acc1 = __builtin_amdgcn_mfma_f32_16x16x32_f16(af.v, bf1.v, acc1, 0, 0, 0);
    }
    { // skip block (k = 544..575)
      H8 bf0, bf1, af;
      bf0.v = *(const h8v*)(wb0 + 544);
      bf1.v = *(const h8v*)(wb1 + 544);
      af.h[0] = fself[0]; af.h[1] = fself[1]; af.h[2] = fself[2]; af.h[3] = fself[3];
      acc0 = __builtin_amdgcn_mfma_f32_16x16x32_f16(af.v, bf0.v, acc0, 0, 0, 0);
      acc1 = __builtin_amdgcn_mfma_f32_16x16x32_f16(af.v, bf1.v, acc1, 0, 0, 0);
    }

    // epilogue: store + BN stats.  D layout: col = lane&15, row = (lane>>4)*4 + r
    float s0 = 0.f, s1 = 0.f, s2 = 0.f, s3 = 0.f;
#pragma unroll
    for (int r = 0; r < 4; r++) {
      float v0 = acc0[r], v1 = acc1[r];
      s0 += v0; s1 += v0 * v0; s2 += v1; s3 += v1 * v1;
      int rd = tile * 16 + q * 4 + r;
      if (rd < MROWS) {
        enc_out[rd * CCH + m] = v0;
        enc_out[rd * CCH + 16 + m] = v1;
      }
    }
    s0 += __shfl_xor(s0, 16, 64); s0 += __shfl_xor(s0, 32, 64);
    s1 += __shfl_xor(s1, 16, 64); s1 += __shfl_xor(s1, 32, 64);
    s2 += __shfl_xor(s2, 16, 64); s2 += __shfl_xor(s2, 32, 64);
    s3 += __shfl_xor(s3, 16, 64); s3 += __shfl_xor(s3, 32, 64);
    if (q == 0) {
      atomicAdd(&sst[m], s0);
      atomicAdd(&sst[32 + m], s1);
      atomicAdd(&sst[16 + m], s2);
      atomicAdd(&sst[48 + m], s3);
    }
  }
  __syncthreads();
  if (threadIdx.x < 64) atomicAdd(&stats[threadIdx.x], sst[threadIdx.x]);
}

// ---------------- BN + leaky-relu ----------------
__global__ void bn_kernel(const float* __restrict__ x, float* __restrict__ out,
                          const float* __restrict__ stats,
                          const float* __restrict__ gamma, const float* __restrict__ beta) {
  int id = blockIdx.x * blockDim.x + threadIdx.x;
  if (id >= MROWS * CCH) return;
  int c = id & 31;
  const float inv = 1.f / (float)MROWS;
  float mu = stats[c] * inv;
  float var = stats[32 + c] * inv - mu * mu;
  float sc = gamma[c] * rsqrtf(var + BNEPS);
  float v = (x[id] - mu) * sc + beta[c];
  out[id] = fmaxf(v, NEG * v);
}

extern "C" void kernel_launch(void* const* d_in, const int* in_sizes, int n_in,
                              void* d_out, int out_size, void* d_ws, size_t ws_size,
                              hipStream_t stream) {
  (void)in_sizes; (void)n_in; (void)out_size; (void)ws_size;
  const float* event_times = (const float*)d_in[0];
  const int*   event_types = (const int*)d_in[1];
  const float* emb   = (const float*)d_in[2];
  const float* k1W   = (const float*)d_in[3];
  const float* k1b   = (const float*)d_in[4];
  const float* k2W   = (const float*)d_in[5];
  const float* k2b   = (const float*)d_in[6];
  const float* k3W   = (const float*)d_in[7];
  const float* k3b   = (const float*)d_in[8];
  const float* skipW = (const float*)d_in[9];
  // d_in[10] = skipb: BN-invariant, dropped
  const float* gamma = (const float*)d_in[11];
  const float* beta  = (const float*)d_in[12];

  float* enc_a = (float*)d_ws;
  float* enc_b = enc_a + (size_t)MROWS * CCH;
  float* stats = enc_b + (size_t)MROWS * CCH;
  int*   maxp  = (int*)(stats + NB_LAYERS * 64);
  _Float16* Wt = (_Float16*)(((uintptr_t)(maxp + 1) + 255) & ~(uintptr_t)255);

  init_kernel<<<2, 256, 0, stream>>>(stats, maxp);
  max_kernel<<<(BSZ * LIN + 255) / 256, 256, 0, stream>>>(event_types, maxp);
  prep_kernel<<<(NB_LAYERS * CCH * KDIM + 255) / 256, 256, 0, stream>>>(k3W, k3b, skipW, Wt);
  embed_kernel<<<(MROWS * CCH + 255) / 256, 256, 0, stream>>>(event_types, emb, maxp, enc_a);

  const int dils[NB_LAYERS] = {1, 2, 4, 8};
  for (int i = 0; i < NB_LAYERS; i++) {
    conv_kernel<<<256, 256, 0, stream>>>(enc_a, enc_b, event_times,
        k1W + i * HCH, k1b + i * HCH, k2W + i * HCH * HCH, k2b + i * HCH,
        Wt + (size_t)i * CCH * KDIM, stats + i * 64, dils[i]);
    float* nout = (i == NB_LAYERS - 1) ? (float*)d_out : enc_a;
    bn_kernel<<<(MROWS * CCH + 255) / 256, 256, 0, stream>>>(
        enc_b, nout, stats + i * 64, gamma + i * CCH, beta + i * CCH);
  }
}